// Round 2
// baseline (9585.709 us; speedup 1.0000x reference)
//
#include <hip/hip_runtime.h>

#define TT    1024   // timesteps
#define BATCH 2048
#define NI    6      // input dim
#define NH    38     // hidden
#define NHP   40     // padded hidden row (10 x float4; pads stay 0)
#define NCLS  8      // classes
#define NB    4      // batches per block
#define BLK   448    // 7 waves: 0-2 layer1, 3-5 layer2, 6 x-prefetch/epilogue
#define GRID  (BATCH / NB)   // 512 blocks = 2 blocks/CU

__device__ __forceinline__ float fsig(float v) {
    return __fdividef(1.0f, 1.0f + __expf(-v));
}

// quad-broadcast lane (base+g) of each 4-lane group; pattern must be literal
#define QB0 0x8000
#define QB1 0x8055
#define QB2 0x80AA
#define QB3 0x80FF
#define QBCAST(v, pat) __int_as_float(__builtin_amdgcn_ds_swizzle(__float_as_int(v), pat))

__global__ __launch_bounds__(BLK, 4) void lstm2_kernel(
    const float* __restrict__ x,
    const float* __restrict__ Wih0, const float* __restrict__ Whh0, const float* __restrict__ b0,
    const float* __restrict__ Wih1, const float* __restrict__ Whh1, const float* __restrict__ b1,
    const float* __restrict__ Wc,   const float* __restrict__ bc,
    float* __restrict__ out)
{
    __shared__ __align__(16) float h1buf[2][NB][NHP];
    __shared__ __align__(16) float h2buf[2][NB][NHP];
    __shared__ float xbuf[4][NB][NI];   // 4-slot x staging, prefetch t+2

    const int tid   = threadIdx.x;
    const int bbase = blockIdx.x * NB;

    // zero both h slots (pads included -> pads stay 0 forever)
    for (int idx = tid; idx < 2 * NB * NHP; idx += BLK) {
        (&h1buf[0][0][0])[idx] = 0.0f;
        (&h2buf[0][0][0])[idx] = 0.0f;
    }
    // preload x(t=0) and x(t=1)
    if (tid < 2 * NB * NI) {
        const int slot = tid / (NB * NI), r = tid % (NB * NI);
        const int b = r / NI, i = r % NI;
        xbuf[slot][b][i] = x[((size_t)(bbase + b) * TT + slot) * NI + i];
    }

    // thread -> (unit u, gate g); gates of a unit occupy one aligned quad
    const int rr   = (tid < 192) ? tid : tid - 192;
    const int u    = rr >> 2;                // 0..47, valid < 38
    const int g    = rr & 3;
    const int uc   = (u < NH) ? u : 0;       // clamp for safe global loads
    const int grow = g * NH + uc;            // gate-row index

    float w[NHP];    // recurrent row: Whh0 (role0) / Whh1 (role1); padded w/ 0
    float wp[NHP];   // role0: Wih0 row (first 6); role1: Wih1 row (padded)
    float bias = 0.0f;
    float cst[NB] = {0.f, 0.f, 0.f, 0.f};
    float qacc[NB];

    if (tid < 192) {
        const float* rw = Whh0 + (size_t)grow * NH;
        #pragma unroll
        for (int k = 0; k < NH; ++k) w[k] = rw[k];
        w[38] = 0.f; w[39] = 0.f;
        const float* rx = Wih0 + (size_t)grow * NI;
        #pragma unroll
        for (int i = 0; i < NI; ++i) wp[i] = rx[i];
        bias = b0[grow];
    } else if (tid < 384) {
        const float* rq = Whh1 + (size_t)grow * NH;
        const float* rp = Wih1 + (size_t)grow * NH;
        #pragma unroll
        for (int k = 0; k < NH; ++k) { w[k] = rq[k]; wp[k] = rp[k]; }
        w[38] = 0.f; w[39] = 0.f; wp[38] = 0.f; wp[39] = 0.f;
        bias = b1[grow];
    }

    // own-gate activation constants: gate 2 is tanh(x) = 2*sigmoid(2x) - 1
    const float k1 = (g == 2) ? 2.0f : 1.0f;
    const float k2 = (g == 2) ? 2.0f : 1.0f;
    const float k3 = (g == 2) ? -1.0f : 0.0f;

    __syncthreads();

    #pragma unroll 2
    for (int t = 0; t < TT; ++t) {
        const int cur = t & 1, prv = cur ^ 1, xs = t & 3;

        // ---------------- phase 1 ----------------
        if (tid < 192) {
            // layer 1: a = b0 + Wih0 x_t + Whh0 h1(t-1), then pointwise via quad
            #pragma unroll
            for (int b = 0; b < NB; ++b) {
                float a = bias;
                #pragma unroll
                for (int i = 0; i < NI; ++i) a += wp[i] * xbuf[xs][b][i];
                const float4* h4 = (const float4*)(&h1buf[prv][b][0]);
                #pragma unroll
                for (int c4 = 0; c4 < 10; ++c4) {
                    const float4 hv = h4[c4];
                    a += w[4*c4+0] * hv.x; a += w[4*c4+1] * hv.y;
                    a += w[4*c4+2] * hv.z; a += w[4*c4+3] * hv.w;
                }
                const float v  = fsig(a * k1) * k2 + k3;
                const float gi = QBCAST(v, QB0);
                const float gf = QBCAST(v, QB1);
                const float gg = QBCAST(v, QB2);
                const float go = QBCAST(v, QB3);
                const float c  = gf * cst[b] + gi * gg;
                cst[b] = c;
                const float h = go * (2.0f * fsig(2.0f * c) - 1.0f);
                if (g == 0 && u < NH) h1buf[cur][b][u] = h;
            }
        } else if (tid < 384) {
            // layer 2 recurrent partial: qacc = Whh1 @ h2(t-1) (indep of h1(t))
            #pragma unroll
            for (int b = 0; b < NB; ++b) {
                float a = 0.0f;
                const float4* h4 = (const float4*)(&h2buf[prv][b][0]);
                #pragma unroll
                for (int c4 = 0; c4 < 10; ++c4) {
                    const float4 hv = h4[c4];
                    a += w[4*c4+0] * hv.x; a += w[4*c4+1] * hv.y;
                    a += w[4*c4+2] * hv.z; a += w[4*c4+3] * hv.w;
                }
                qacc[b] = a;
            }
        } else {
            // x prefetch, 2 steps ahead (latency hidden across 2 full steps)
            const int s = tid - 384;
            if (s < NB * NI && t + 2 < TT) {
                const int b = s / NI, i = s % NI;
                xbuf[(t + 2) & 3][b][i] = x[((size_t)(bbase + b) * TT + (t + 2)) * NI + i];
            }
        }
        __syncthreads();

        // ---------------- phase 2 ----------------
        if (tid >= 192 && tid < 384) {
            // layer 2: a = qacc + b1 + Wih1 h1(t), then pointwise via quad
            #pragma unroll
            for (int b = 0; b < NB; ++b) {
                float a = qacc[b] + bias;
                const float4* h4 = (const float4*)(&h1buf[cur][b][0]);
                #pragma unroll
                for (int c4 = 0; c4 < 10; ++c4) {
                    const float4 hv = h4[c4];
                    a += wp[4*c4+0] * hv.x; a += wp[4*c4+1] * hv.y;
                    a += wp[4*c4+2] * hv.z; a += wp[4*c4+3] * hv.w;
                }
                const float v  = fsig(a * k1) * k2 + k3;
                const float gi = QBCAST(v, QB0);
                const float gf = QBCAST(v, QB1);
                const float gg = QBCAST(v, QB2);
                const float go = QBCAST(v, QB3);
                const float c  = gf * cst[b] + gi * gg;
                cst[b] = c;
                const float h = go * (2.0f * fsig(2.0f * c) - 1.0f);
                if (g == 0 && u < NH) h2buf[cur][b][u] = h;
            }
        }
        __syncthreads();
    }

    // epilogue: out = h2(T-1) @ Wc.T + bc ; TT-1 is odd -> slot 1
    if (tid < NB * NCLS) {
        const int b = tid / NCLS, c = tid % NCLS;
        float acc = bc[c];
        #pragma unroll
        for (int k = 0; k < NH; ++k) acc += Wc[c * NH + k] * h2buf[1][b][k];
        out[(size_t)(bbase + b) * NCLS + c] = acc;
    }
}

extern "C" void kernel_launch(void* const* d_in, const int* in_sizes, int n_in,
                              void* d_out, int out_size, void* d_ws, size_t ws_size,
                              hipStream_t stream) {
    const float* x    = (const float*)d_in[0];
    const float* Wih0 = (const float*)d_in[1];
    const float* Whh0 = (const float*)d_in[2];
    const float* b0   = (const float*)d_in[3];
    const float* Wih1 = (const float*)d_in[4];
    const float* Whh1 = (const float*)d_in[5];
    const float* b1   = (const float*)d_in[6];
    const float* Wc   = (const float*)d_in[7];
    const float* bc   = (const float*)d_in[8];
    float* out = (float*)d_out;

    hipLaunchKernelGGL(lstm2_kernel, dim3(GRID), dim3(BLK), 0, stream,
                       x, Wih0, Whh0, b0, Wih1, Whh1, b1, Wc, bc, out);
}